// Round 4
// baseline (18599.466 us; speedup 1.0000x reference)
//
#include <hip/hip_runtime.h>
#include <cstddef>
#include <cstdint>

// VQ-VAE 1D forward. Encoder fp64 (naive independent stages, exonerated in r3).
// VQ now EMULATES the reference's fp32 distance formula including the z·z constant
// (dist = fl32(fl32(zsq+csq) - fl32(2*zc))) with first-min tie-break, because the
// reference's fp32 ties (ulp(dist)~1e-6 ~ inter-code gaps) decide a few codes.
// Decoder + losses fp32 (validated by output-0 pass).
// d_out: x_hat (B,T,36) | codes as float (B,512) | [loss_vq, perplexity, loss_pos, loss_dir]

#define TID ((int)threadIdx.x)
#define NB 8  // batches per chunk

__device__ __forceinline__ float silu_f(float y) { return y / (1.f + expf(-y)); }

// ================= weight prep =================
__global__ void perm_oik_iko_f64(const float* __restrict__ src, double* __restrict__ dst,
                                 int R, int O, int I, int K) {
  int n = R * O * I * K;
  for (int idx = blockIdx.x * blockDim.x + TID; idx < n; idx += gridDim.x * blockDim.x) {
    int o = idx % O;
    int k = (idx / O) % K;
    int i = (idx / (O * K)) % I;
    int r = idx / (O * K * I);
    dst[idx] = (double)src[((r * O + o) * I + i) * K + k];
  }
}

__global__ void perm_oik_iko(const float* __restrict__ src, float* __restrict__ dst,
                             int R, int O, int I, int K) {
  int n = R * O * I * K;
  for (int idx = blockIdx.x * blockDim.x + TID; idx < n; idx += gridDim.x * blockDim.x) {
    int o = idx % O;
    int k = (idx / O) % K;
    int i = (idx / (O * K)) % I;
    int r = idx / (O * K * I);
    dst[idx] = src[((r * O + o) * I + i) * K + k];
  }
}

__global__ void perm_decout(const float* __restrict__ src, float* __restrict__ dst) {
  int n = 256 * 36 * 4;
  for (int idx = blockIdx.x * blockDim.x + TID; idx < n; idx += gridDim.x * blockDim.x) {
    int k = idx & 3;
    int o = (idx >> 2) % 36;
    int i = idx / 144;
    dst[idx] = (k < 3) ? src[(o * 256 + i) * 3 + k] : 0.f;
  }
}

__global__ void zero_k(float* p, int n) {
  int i = blockIdx.x * blockDim.x + TID;
  if (i < n) p[i] = 0.f;
}

// csq[j] = fp32 sequential sum of fl(c*c) — mirrors (codebook*codebook).sum(1) in fp32
__global__ void csq_f32(const float* __restrict__ cb, float* __restrict__ csq) {
  int j = blockIdx.x * blockDim.x + TID;
  if (j < 1024) {
    float s = 0.f;
    for (int c = 0; c < 128; c++) { float v = cb[j * 128 + c]; s += v * v; }
    csq[j] = s;
  }
}

// ================= NAIVE encoder-unique kernels (fp64) =========
__global__ __launch_bounds__(256) void nv_conv_in(const float* __restrict__ x,
                                                  const float* __restrict__ w,
                                                  const float* __restrict__ bias,
                                                  double* __restrict__ out) {
  int b = blockIdx.x >> 7;
  int t0 = (blockIdx.x & 127) << 4;
  int o = TID;
  double acc[16];
#pragma unroll
  for (int u = 0; u < 16; u++) acc[u] = 0.;
  for (int i = 0; i < 36; i++) {
#pragma unroll
    for (int k = 0; k < 3; k++) {
      double wv = (double)w[(o * 36 + i) * 3 + k];
#pragma unroll
      for (int u = 0; u < 16; u++) {
        int t = t0 + u + k - 1;
        double xv = (t >= 0 && t < 2048) ? (double)x[((size_t)(b * 2048 + t)) * 36 + i] : 0.;
        acc[u] += wv * xv;
      }
    }
  }
  double bv = (double)bias[o];
  size_t row = ((size_t)(b * 256 + o)) * 2048 + t0;
#pragma unroll
  for (int u = 0; u < 16; u++) out[row + u] = acc[u] + bv;
}

__global__ __launch_bounds__(256) void nv_down(const double* __restrict__ in,
                                               const float* __restrict__ w,
                                               const float* __restrict__ bias,
                                               double* __restrict__ out) {
  int b = blockIdx.x >> 6;
  int to0 = (blockIdx.x & 63) << 3;
  int o = TID;
  double acc[8];
#pragma unroll
  for (int u = 0; u < 8; u++) acc[u] = 0.;
  for (int i = 0; i < 256; i++) {
    const float* wr = w + ((size_t)o * 256 + i) * 8;
    const double* hr = in + ((size_t)(b * 256 + i)) * 2048;
#pragma unroll
    for (int k = 0; k < 8; k++) {
      double wv = (double)wr[k];
#pragma unroll
      for (int u = 0; u < 8; u++) {
        int s = ((to0 + u) << 2) + k - 2;
        double hv = (s >= 0 && s < 2048) ? hr[s] : 0.;
        acc[u] += wv * hv;
      }
    }
  }
  double bv = (double)bias[o];
  size_t row = ((size_t)(b * 256 + o)) * 512 + to0;
#pragma unroll
  for (int u = 0; u < 8; u++) out[row + u] = acc[u] + bv;
}

__global__ __launch_bounds__(128) void nv_1x1enc(const double* __restrict__ in,
                                                 const float* __restrict__ w,
                                                 const float* __restrict__ bias,
                                                 double* __restrict__ out) {
  int b = blockIdx.x >> 5;
  int to0 = (blockIdx.x & 31) << 4;
  int o = TID;
  double acc[16];
#pragma unroll
  for (int u = 0; u < 16; u++) acc[u] = 0.;
  for (int i = 0; i < 256; i++) {
    double wv = (double)w[o * 256 + i];
    const double* hr = in + ((size_t)(b * 256 + i)) * 512 + to0;
#pragma unroll
    for (int u = 0; u < 16; u++) acc[u] += wv * hr[u];
  }
  double bv = (double)bias[o];
  size_t row = ((size_t)(b * 128 + o)) * 512 + to0;
#pragma unroll
  for (int u = 0; u < 16; u++) out[row + u] = acc[u] + bv;
}

// ===== VQ: fp32 emulation of reference's dist = zsq + csq - 2*(z@c^T), first-min =====
__global__ __launch_bounds__(256) void nv_vq_f32(const double* __restrict__ zE,
                                                 const float* __restrict__ cb,
                                                 const float* __restrict__ csq,
                                                 int* __restrict__ codes) {
  int n = blockIdx.x * blockDim.x + TID;  // 16384 points
  if (n >= 16384) return;
  int b = n >> 9, t = n & 511;
  const double* zp = zE + ((size_t)b * 128) * 512 + t;
  // z vector in fp32 (reference z_e is fp32)
  float z[128];
  for (int c = 0; c < 128; c++) z[c] = (float)zp[(size_t)c * 512];
  // zsq in fp32, sequential (uniform constant across codes -> tie-robust)
  float zsq = 0.f;
  for (int c = 0; c < 128; c++) zsq += z[c] * z[c];
  float best = 3.4e38f;
  int bj = 0;
  for (int j = 0; j < 1024; j++) {
    const float* cr = cb + (size_t)j * 128;
    float zc = 0.f;
    for (int c = 0; c < 128; c++) zc += z[c] * cr[c];
    float A = zsq + csq[j];     // fl32(zsq + csq)
    float B = 2.0f * zc;        // fl32(2*zc) (exact scale)
    float d = A - B;            // fl32(A - B)
    if (d < best) { best = d; bj = j; }  // ascending j, strict < == first-min (jnp.argmin)
  }
  codes[n] = bj;
}

// ================= fp64 res-block kernels =================
__global__ __launch_bounds__(256) void gn_silu_f64(const double* __restrict__ in, double* __restrict__ out,
                                                   const float* __restrict__ gamma, const float* __restrict__ beta) {
  int b = blockIdx.x >> 3, g = blockIdx.x & 7;
  size_t base = ((size_t)b * 256 + g * 32) * 2048;
  const double2* src = (const double2*)(in + base);
  double2* dst = (double2*)(out + base);
  double s1 = 0., s2 = 0.;
  for (int f = TID; f < 32768; f += 256) {
    double2 v = src[f];
    s1 += v.x + v.y;
    s2 += v.x * v.x + v.y * v.y;
  }
  __shared__ double r1[256], r2[256];
  r1[TID] = s1; r2[TID] = s2;
  __syncthreads();
  for (int st = 128; st > 0; st >>= 1) {
    if (TID < st) { r1[TID] += r1[TID + st]; r2[TID] += r2[TID + st]; }
    __syncthreads();
  }
  double mu = r1[0] * (1.0 / 65536.0);
  double var = r2[0] * (1.0 / 65536.0) - mu * mu;
  double rs = 1.0 / sqrt(var + 1e-5);
  for (int f = TID; f < 32768; f += 256) {
    int c = g * 32 + (f >> 10);
    double a = rs * (double)gamma[c];
    double bb = (double)beta[c] - mu * a;
    double2 v = src[f];
    double2 o;
    double y0 = v.x * a + bb, y1 = v.y * a + bb;
    o.x = y0 / (1.0 + exp(-y0));
    o.y = y1 / (1.0 + exp(-y1));
    dst[f] = o;
  }
}

__global__ __launch_bounds__(256) void conv3_f64(const double* __restrict__ in, const double* __restrict__ wT,
                                                 const float* __restrict__ bias, const double* __restrict__ src,
                                                 double* __restrict__ out) {
  int b = blockIdx.x >> 5;
  int t0 = (blockIdx.x & 31) << 6;
  int o0 = blockIdx.y << 6;
  int tx = TID & 15, oy = TID >> 4;
  __shared__ double ins[16][68];
  __shared__ double wsl[16 * 192];
  double acc[4][4];
#pragma unroll
  for (int m = 0; m < 4; m++)
#pragma unroll
    for (int n = 0; n < 4; n++) acc[m][n] = 0.;
  for (int ic0 = 0; ic0 < 256; ic0 += 16) {
    __syncthreads();
    for (int idx = TID; idx < 16 * 66; idx += 256) {
      int r = idx / 66, c = idx % 66;
      int t = t0 - 1 + c;
      double v = 0.;
      if (t >= 0 && t < 2048) v = in[(((size_t)((b << 8) + ic0 + r)) << 11) + t];
      ins[r][c] = v;
    }
    for (int idx = TID; idx < 16 * 192; idx += 256) {
      int o = idx & 63;
      int kk = (idx >> 6) % 3;
      int i = idx / 192;
      wsl[idx] = wT[((ic0 + i) * 3 + kk) * 256 + o0 + o];
    }
    __syncthreads();
#pragma unroll 4
    for (int i = 0; i < 16; i++) {
      double xv[6];
#pragma unroll
      for (int q = 0; q < 6; q++) xv[q] = ins[i][(tx << 2) + q];
      const double* wrow = &wsl[i * 192];
      double wv[3][4];
#pragma unroll
      for (int kk = 0; kk < 3; kk++)
#pragma unroll
        for (int m = 0; m < 4; m++) wv[kk][m] = wrow[kk * 64 + (oy << 2) + m];
#pragma unroll
      for (int m = 0; m < 4; m++)
#pragma unroll
        for (int n = 0; n < 4; n++)
          acc[m][n] += wv[0][m] * xv[n] + wv[1][m] * xv[n + 1] + wv[2][m] * xv[n + 2];
    }
  }
  int obase = o0 + (oy << 2);
#pragma unroll
  for (int m = 0; m < 4; m++) {
    int o = obase + m;
    double bv = (double)bias[o];
    size_t rowo = (((size_t)((b << 8) + o)) << 11) + t0 + (tx << 2);
#pragma unroll
    for (int n = 0; n < 4; n++) {
      double v = acc[m][n] + bv;
      if (src) v += src[rowo + n];
      out[rowo + n] = v;
    }
  }
}

// ================= VQ bookkeeping =================
__global__ void count_k(const int* __restrict__ codes, float* __restrict__ counts) {
  int n = blockIdx.x * blockDim.x + TID;
  if (n < 16384) atomicAdd(&counts[codes[n]], 1.f);
}

__global__ __launch_bounds__(256) void gather_f64(const float* __restrict__ cb, const int* __restrict__ codes,
                                                  const double* __restrict__ zE, float* __restrict__ zQ,
                                                  float* __restrict__ vqsum) {
  double part = 0.;
  const int total = 32 * 128 * 512;
  for (int idx = blockIdx.x * blockDim.x + TID; idx < total; idx += gridDim.x * blockDim.x) {
    int t = idx & 511;
    int c = (idx >> 9) & 127;
    int b = idx >> 16;
    int code = codes[(b << 9) + t];
    float q = cb[code * 128 + c];
    double d = (double)q - zE[idx];
    zQ[idx] = q;
    part += d * d;
  }
  __shared__ double red[256];
  red[TID] = part;
  __syncthreads();
  for (int st = 128; st > 0; st >>= 1) {
    if (TID < st) red[TID] += red[TID + st];
    __syncthreads();
  }
  if (TID == 0) atomicAdd(vqsum, (float)red[0]);
}

// ================= fp32 decoder (validated) =================
__global__ __launch_bounds__(256) void gn_silu_k(const float* __restrict__ in, float* __restrict__ out,
                                                 const float* __restrict__ gamma, const float* __restrict__ beta) {
  int b = blockIdx.x >> 3, g = blockIdx.x & 7;
  size_t base = ((size_t)b * 256 + g * 32) * 2048;
  const float4* src = (const float4*)(in + base);
  float4* dst = (float4*)(out + base);
  float s1 = 0.f, s2 = 0.f;
  for (int f = TID; f < 16384; f += 256) {
    float4 v = src[f];
    s1 += v.x + v.y + v.z + v.w;
    s2 += v.x * v.x + v.y * v.y + v.z * v.z + v.w * v.w;
  }
  __shared__ float r1[256], r2[256];
  r1[TID] = s1; r2[TID] = s2;
  __syncthreads();
  for (int st = 128; st > 0; st >>= 1) {
    if (TID < st) { r1[TID] += r1[TID + st]; r2[TID] += r2[TID + st]; }
    __syncthreads();
  }
  float mu = r1[0] * (1.f / 65536.f);
  float var = r2[0] * (1.f / 65536.f) - mu * mu;
  float rs = rsqrtf(var + 1e-5f);
  for (int f = TID; f < 16384; f += 256) {
    int c = g * 32 + (f >> 9);
    float a = rs * gamma[c];
    float bb = beta[c] - mu * a;
    float4 v = src[f];
    float4 o;
    o.x = silu_f(v.x * a + bb);
    o.y = silu_f(v.y * a + bb);
    o.z = silu_f(v.z * a + bb);
    o.w = silu_f(v.w * a + bb);
    dst[f] = o;
  }
}

__global__ __launch_bounds__(256) void conv3_k(const float* __restrict__ in, const float* __restrict__ wT,
                                               const float* __restrict__ bias, const float* __restrict__ src,
                                               float* __restrict__ out) {
  int b = blockIdx.x >> 5;
  int t0 = (blockIdx.x & 31) << 6;
  int o0 = blockIdx.y << 6;
  int tx = TID & 15, oy = TID >> 4;
  __shared__ float ins[32][68];
  __shared__ float wsl[32 * 192];
  float acc[4][4];
#pragma unroll
  for (int m = 0; m < 4; m++)
#pragma unroll
    for (int n = 0; n < 4; n++) acc[m][n] = 0.f;
  for (int ic0 = 0; ic0 < 256; ic0 += 32) {
    __syncthreads();
    for (int idx = TID; idx < 32 * 66; idx += 256) {
      int r = idx / 66, c = idx % 66;
      int t = t0 - 1 + c;
      float v = 0.f;
      if (t >= 0 && t < 2048) v = in[(((size_t)((b << 8) + ic0 + r)) << 11) + t];
      ins[r][c] = v;
    }
    for (int idx = TID; idx < 32 * 192; idx += 256) {
      int o = idx & 63;
      int kk = (idx >> 6) % 3;
      int i = idx / 192;
      wsl[idx] = wT[((ic0 + i) * 3 + kk) * 256 + o0 + o];
    }
    __syncthreads();
#pragma unroll 4
    for (int i = 0; i < 32; i++) {
      float xv[6];
      float4 x4 = *(const float4*)&ins[i][tx << 2];
      xv[0] = x4.x; xv[1] = x4.y; xv[2] = x4.z; xv[3] = x4.w;
      xv[4] = ins[i][(tx << 2) + 4];
      xv[5] = ins[i][(tx << 2) + 5];
      const float* wrow = &wsl[i * 192];
      float wv[3][4];
      *(float4*)wv[0] = *(const float4*)&wrow[oy << 2];
      *(float4*)wv[1] = *(const float4*)&wrow[64 + (oy << 2)];
      *(float4*)wv[2] = *(const float4*)&wrow[128 + (oy << 2)];
#pragma unroll
      for (int m = 0; m < 4; m++)
#pragma unroll
        for (int n = 0; n < 4; n++)
          acc[m][n] += wv[0][m] * xv[n] + wv[1][m] * xv[n + 1] + wv[2][m] * xv[n + 2];
    }
  }
  int obase = o0 + (oy << 2);
#pragma unroll
  for (int m = 0; m < 4; m++) {
    int o = obase + m;
    float bv = bias[o];
    size_t rowo = (((size_t)((b << 8) + o)) << 11) + t0 + (tx << 2);
#pragma unroll
    for (int n = 0; n < 4; n++) {
      float v = acc[m][n] + bv;
      if (src) v += src[rowo + n];
      out[rowo + n] = v;
    }
  }
}

__global__ __launch_bounds__(256) void conv1x1_k(const float* __restrict__ in, const float* __restrict__ wIO,
                                                 const float* __restrict__ bias, float* __restrict__ out,
                                                 int Kc, int O) {
  int b = blockIdx.x >> 3;
  int t0 = (blockIdx.x & 7) << 6;
  int o0 = blockIdx.y << 6;
  int tx = TID & 15, oy = TID >> 4;
  __shared__ float xs[32][64];
  __shared__ float wsd[32][64];
  float acc[4][4];
#pragma unroll
  for (int m = 0; m < 4; m++)
#pragma unroll
    for (int n = 0; n < 4; n++) acc[m][n] = 0.f;
  for (int ic0 = 0; ic0 < Kc; ic0 += 32) {
    __syncthreads();
    for (int idx = TID; idx < 2048; idx += 256) {
      int r = idx >> 6, c = idx & 63;
      xs[r][c] = in[((size_t)(b * Kc + ic0 + r) << 9) + t0 + c];
      wsd[r][c] = wIO[(ic0 + r) * O + o0 + c];
    }
    __syncthreads();
#pragma unroll 8
    for (int i = 0; i < 32; i++) {
      float4 xvv = *(const float4*)&xs[i][tx << 2];
      float4 wvv = *(const float4*)&wsd[i][oy << 2];
      float xv[4] = {xvv.x, xvv.y, xvv.z, xvv.w};
      float wv[4] = {wvv.x, wvv.y, wvv.z, wvv.w};
#pragma unroll
      for (int m = 0; m < 4; m++)
#pragma unroll
        for (int n = 0; n < 4; n++) acc[m][n] += wv[m] * xv[n];
    }
  }
#pragma unroll
  for (int m = 0; m < 4; m++) {
    int o = o0 + (oy << 2) + m;
    float bv = bias[o];
    size_t rowo = ((size_t)(b * O + o) << 9) + t0 + (tx << 2);
#pragma unroll
    for (int n = 0; n < 4; n++) out[rowo + n] = acc[m][n] + bv;
  }
}

__global__ __launch_bounds__(256) void conv_up_k(const float* __restrict__ in, const float* __restrict__ w,
                                                 const float* __restrict__ bias, float* __restrict__ out) {
  int b = blockIdx.x / 17;
  int s0 = (blockIdx.x % 17) << 5;
  int o0 = blockIdx.y << 6;
  int tx = TID & 15, oy = TID >> 4;
  __shared__ float ins[16][36];
  __shared__ float wsl[16 * 512];
  float acc[2][4][4];
#pragma unroll
  for (int j = 0; j < 2; j++)
#pragma unroll
    for (int m = 0; m < 4; m++)
#pragma unroll
      for (int r = 0; r < 4; r++) acc[j][m][r] = 0.f;
  for (int ic0 = 0; ic0 < 256; ic0 += 16) {
    __syncthreads();
    for (int idx = TID; idx < 16 * 34; idx += 256) {
      int r = idx / 34, c = idx % 34;
      int s = s0 - 1 + c;
      float v = 0.f;
      if (s >= 0 && s < 512) v = in[(((size_t)((b << 8) + ic0 + r)) << 9) + s];
      ins[r][c] = v;
    }
    for (int idx = TID; idx < 8192; idx += 256) {
      int rr = idx & 3;
      int o = (idx >> 2) & 63;
      int h = (idx >> 8) & 1;
      int i = idx >> 9;
      wsl[idx] = w[(((size_t)(ic0 + i)) << 11) + ((size_t)(o0 + o) << 3) + (h << 2) + rr];
    }
    __syncthreads();
#pragma unroll 2
    for (int i = 0; i < 16; i++) {
      float x0 = ins[i][2 * tx], x1 = ins[i][2 * tx + 1], x2 = ins[i][2 * tx + 2];
#pragma unroll
      for (int m = 0; m < 4; m++) {
        int om = (oy << 2) + m;
        float4 wa4 = *(const float4*)&wsl[(i << 9) + (om << 2)];
        float4 wb4 = *(const float4*)&wsl[(i << 9) + 256 + (om << 2)];
        float wa[4] = {wa4.x, wa4.y, wa4.z, wa4.w};
        float wb[4] = {wb4.x, wb4.y, wb4.z, wb4.w};
#pragma unroll
        for (int r = 0; r < 4; r++) {
          acc[0][m][r] += x1 * wa[r] + x0 * wb[r];
          acc[1][m][r] += x2 * wa[r] + x1 * wb[r];
        }
      }
    }
  }
#pragma unroll
  for (int j = 0; j < 2; j++) {
    int s1 = s0 + (tx << 1) + j;
#pragma unroll
    for (int m = 0; m < 4; m++) {
      int o = o0 + (oy << 2) + m;
      float bv = bias[o];
#pragma unroll
      for (int r = 0; r < 4; r++) {
        int t = (s1 << 2) + r - 2;
        if (t >= 0 && t < 2048) out[(((size_t)((b << 8) + o)) << 11) + t] = acc[j][m][r] + bv;
      }
    }
  }
}

__global__ __launch_bounds__(256) void conv_out_k(const float* __restrict__ in, const float* __restrict__ wP,
                                                  const float* __restrict__ bias, float* __restrict__ xhat) {
  int b = blockIdx.x >> 5;
  int t0 = (blockIdx.x & 31) << 6;
  int tx = TID & 63, oy = TID >> 6;
  __shared__ float ins[32][68];
  __shared__ float wsl[32 * 144];
  float acc[9];
#pragma unroll
  for (int m = 0; m < 9; m++) acc[m] = 0.f;
  for (int ic0 = 0; ic0 < 256; ic0 += 32) {
    __syncthreads();
    for (int idx = TID; idx < 32 * 66; idx += 256) {
      int r = idx / 66, c = idx % 66;
      int t = t0 - 1 + c;
      float v = 0.f;
      if (t >= 0 && t < 2048) v = in[(((size_t)((b << 8) + ic0 + r)) << 11) + t];
      ins[r][c] = v;
    }
    for (int idx = TID; idx < 32 * 144; idx += 256) {
      wsl[idx] = wP[ic0 * 144 + idx];
    }
    __syncthreads();
#pragma unroll 4
    for (int i = 0; i < 32; i++) {
      float x0 = ins[i][tx], x1 = ins[i][tx + 1], x2 = ins[i][tx + 2];
#pragma unroll
      for (int m = 0; m < 9; m++) {
        int o = oy * 9 + m;
        float4 wv = *(const float4*)&wsl[(i * 36 + o) << 2];
        acc[m] += wv.x * x0 + wv.y * x1 + wv.z * x2;
      }
    }
  }
  size_t orow = ((size_t)(b << 11) + t0 + tx) * 36;
#pragma unroll
  for (int m = 0; m < 9; m++) {
    int o = oy * 9 + m;
    xhat[orow + o] = acc[m] + bias[o];
  }
}

// ================= losses =================
__global__ __launch_bounds__(256) void loss_k(const float* __restrict__ x, const float* __restrict__ xh,
                                              const float* __restrict__ mask, float* __restrict__ scal) {
  float pos = 0.f, dir = 0.f, ms = 0.f;
  for (int n = blockIdx.x * blockDim.x + TID; n < 65536; n += gridDim.x * blockDim.x) {
    const float* xp = x + (size_t)n * 36;
    const float* hp = xh + (size_t)n * 36;
    float a[36], h[36];
#pragma unroll
    for (int d4 = 0; d4 < 36; d4 += 4) {
      *(float4*)&a[d4] = *(const float4*)&xp[d4];
      *(float4*)&h[d4] = *(const float4*)&hp[d4];
    }
#pragma unroll
    for (int d = 0; d < 36; d++) {
      if (d < 21 || (d >= 27 && d < 30)) {
        float df = h[d] - a[d];
        float ad = fabsf(df);
        pos += (ad < 1.f) ? 0.5f * df * df : ad - 0.5f;
      }
    }
    float mL = mask[2 * (size_t)n], mR = mask[2 * (size_t)n + 1];
    const int vb[4] = {21, 24, 30, 33};
    float mv[4] = {mL, mL, mR, mR};
#pragma unroll
    for (int v = 0; v < 4; v++) {
      int o = vb[v];
      float ax = a[o], ay = a[o + 1], az = a[o + 2];
      float hx = h[o], hy = h[o + 1], hz = h[o + 2];
      float an = sqrtf(ax * ax + ay * ay + az * az) + 1e-8f;
      float hn = sqrtf(hx * hx + hy * hy + hz * hz) + 1e-8f;
      float cs = (ax * hx + ay * hy + az * hz) / (an * hn);
      dir += (1.f - cs) * mv[v];
    }
    ms += 2.f * (mL + mR);
  }
  __shared__ float rp[256], rd[256], rm[256];
  rp[TID] = pos; rd[TID] = dir; rm[TID] = ms;
  __syncthreads();
  for (int st = 128; st > 0; st >>= 1) {
    if (TID < st) { rp[TID] += rp[TID + st]; rd[TID] += rd[TID + st]; rm[TID] += rm[TID + st]; }
    __syncthreads();
  }
  if (TID == 0) {
    atomicAdd(&scal[1], rp[0]);
    atomicAdd(&scal[2], rd[0]);
    atomicAdd(&scal[3], rm[0]);
  }
}

__global__ __launch_bounds__(256) void finalize_k(const float* __restrict__ counts, const float* __restrict__ scal,
                                                  float* __restrict__ tail) {
  __shared__ float red[256];
  float s = 0.f;
  for (int j = TID; j < 1024; j += 256) {
    float avg = counts[j] * (1.f / 16384.f);
    s += avg * logf(avg + 1e-10f);
  }
  red[TID] = s;
  __syncthreads();
  for (int st = 128; st > 0; st >>= 1) {
    if (TID < st) red[TID] += red[TID + st];
    __syncthreads();
  }
  if (TID == 0) {
    tail[0] = 1.25f * scal[0] * (1.f / 2097152.f);
    tail[1] = expf(-red[0]);
    tail[2] = scal[1] * (1.f / 65536.f);
    tail[3] = scal[2] / fmaxf(scal[3], 1.f);
  }
}

__global__ void codesf_k(const int* __restrict__ codes, float* __restrict__ o) {
  int n = blockIdx.x * blockDim.x + TID;
  if (n < 16384) o[n] = (float)codes[n];
}

// ================= host =================
extern "C" void kernel_launch(void* const* d_in, const int* in_sizes, int n_in,
                              void* d_out, int out_size, void* d_ws, size_t ws_size,
                              hipStream_t stream) {
  const float* x = (const float*)d_in[0];
  const float* mask = (const float*)d_in[1];
  const float* enc_in_w = (const float*)d_in[2];
  const float* enc_in_b = (const float*)d_in[3];
  const float* enc_gn1_g = (const float*)d_in[4];
  const float* enc_gn1_b = (const float*)d_in[5];
  const float* enc_c1_w = (const float*)d_in[6];
  const float* enc_c1_b = (const float*)d_in[7];
  const float* enc_gn2_g = (const float*)d_in[8];
  const float* enc_gn2_b = (const float*)d_in[9];
  const float* enc_c2_w = (const float*)d_in[10];
  const float* enc_c2_b = (const float*)d_in[11];
  const float* down_w = (const float*)d_in[12];
  const float* down_b = (const float*)d_in[13];
  const float* enc_out_w = (const float*)d_in[14];
  const float* enc_out_b = (const float*)d_in[15];
  const float* codebook = (const float*)d_in[16];
  const float* dec_in_w = (const float*)d_in[17];
  const float* dec_in_b = (const float*)d_in[18];
  const float* up_w = (const float*)d_in[19];
  const float* up_b = (const float*)d_in[20];
  const float* dec_gn1_g = (const float*)d_in[21];
  const float* dec_gn1_b = (const float*)d_in[22];
  const float* dec_c1_w = (const float*)d_in[23];
  const float* dec_c1_b = (const float*)d_in[24];
  const float* dec_gn2_g = (const float*)d_in[25];
  const float* dec_gn2_b = (const float*)d_in[26];
  const float* dec_c2_w = (const float*)d_in[27];
  const float* dec_c2_b = (const float*)d_in[28];
  const float* dec_out_w = (const float*)d_in[29];
  const float* dec_out_b = (const float*)d_in[30];

  char* W = (char*)d_ws;
  double* zE_d = (double*)(W + 0);                    // 16,777,216 B
  float* zQ = (float*)(W + 16777216);                 // 8,388,608 B
  int* codes = (int*)(W + 25165824);                  // 65,536 B
  float* counts = (float*)(W + 25231360);             // 4,096 B
  float* scal = (float*)(W + 25235456);               // 32 B
  float* csq = (float*)(W + 25235488);                // 4,096 B
  double* wd_c1 = (double*)(W + 25239584);            // 6,291,456 B
  double* wd_c2 = (double*)(W + 31531040);            // 6,291,456 B
  float* wf_dec_in = (float*)(W + 37822496);          // 131,072 B
  float* wf_dec_c1 = (float*)(W + 37953568);          // 3,145,728 B
  float* wf_dec_c2 = (float*)(W + 41099296);          // 3,145,728 B
  float* wf_dec_out = (float*)(W + 44245024);         // 147,456 B
  double* e0 = (double*)(W + 50331648);
  double* e1 = (double*)(W + 50331648 + 33554432);
  double* e2 = (double*)(W + 50331648 + 2 * (size_t)33554432);
  float* f0 = (float*)(W + 50331648);
  float* f1 = (float*)(W + 50331648 + 16777216);
  float* f2 = (float*)(W + 50331648 + 2 * (size_t)16777216);
  float* dech = (float*)(W + 50331648 + 3 * (size_t)16777216);

  dim3 blk(256);
  zero_k<<<dim3(5), blk, 0, stream>>>(counts, 1032);
  perm_oik_iko_f64<<<dim3(1024), blk, 0, stream>>>(enc_c1_w, wd_c1, 4, 256, 256, 3);
  perm_oik_iko_f64<<<dim3(1024), blk, 0, stream>>>(enc_c2_w, wd_c2, 4, 256, 256, 3);
  perm_oik_iko<<<dim3(128), blk, 0, stream>>>(dec_in_w, wf_dec_in, 1, 256, 128, 1);
  perm_oik_iko<<<dim3(1024), blk, 0, stream>>>(dec_c1_w, wf_dec_c1, 4, 256, 256, 3);
  perm_oik_iko<<<dim3(1024), blk, 0, stream>>>(dec_c2_w, wf_dec_c2, 4, 256, 256, 3);
  perm_decout<<<dim3(64), blk, 0, stream>>>(dec_out_w, wf_dec_out);
  csq_f32<<<dim3(4), blk, 0, stream>>>(codebook, csq);

  // ---- encoder (fp64), 4 chunks of NB=8 batches ----
  for (int ci = 0; ci < 4; ci++) {
    int b0 = ci * NB;
    nv_conv_in<<<dim3(NB * 128), blk, 0, stream>>>(x + (size_t)b0 * 2048 * 36, enc_in_w, enc_in_b, e0);
    for (int i = 0; i < 4; i++) {
      gn_silu_f64<<<dim3(NB * 8), blk, 0, stream>>>(e0, e1, enc_gn1_g + i * 256, enc_gn1_b + i * 256);
      conv3_f64<<<dim3(NB * 32, 4), blk, 0, stream>>>(e1, wd_c1 + i * 196608, enc_c1_b + i * 256, nullptr, e2);
      gn_silu_f64<<<dim3(NB * 8), blk, 0, stream>>>(e2, e1, enc_gn2_g + i * 256, enc_gn2_b + i * 256);
      conv3_f64<<<dim3(NB * 32, 4), blk, 0, stream>>>(e1, wd_c2 + i * 196608, enc_c2_b + i * 256, e0, e0);
    }
    nv_down<<<dim3(NB * 64), blk, 0, stream>>>(e0, down_w, down_b, e1);
    nv_1x1enc<<<dim3(NB * 32), dim3(128), 0, stream>>>(e1, enc_out_w, enc_out_b, zE_d + (size_t)b0 * 128 * 512);
  }

  // ---- quantize: fp32-formula-emulating argmin ----
  nv_vq_f32<<<dim3(64), blk, 0, stream>>>(zE_d, codebook, csq, codes);
  count_k<<<dim3(64), blk, 0, stream>>>(codes, counts);
  gather_f64<<<dim3(512), blk, 0, stream>>>(codebook, codes, zE_d, zQ, &scal[0]);

  // ---- decoder (fp32), 4 chunks ----
  float* xhat = (float*)d_out;
  for (int ci = 0; ci < 4; ci++) {
    int b0 = ci * NB;
    conv1x1_k<<<dim3(NB * 8, 4), blk, 0, stream>>>(zQ + (size_t)b0 * 128 * 512, wf_dec_in, dec_in_b, dech, 128, 256);
    conv_up_k<<<dim3(NB * 17, 4), blk, 0, stream>>>(dech, up_w, up_b, f0);
    for (int i = 0; i < 4; i++) {
      gn_silu_k<<<dim3(NB * 8), blk, 0, stream>>>(f0, f1, dec_gn1_g + i * 256, dec_gn1_b + i * 256);
      conv3_k<<<dim3(NB * 32, 4), blk, 0, stream>>>(f1, wf_dec_c1 + i * 196608, dec_c1_b + i * 256, nullptr, f2);
      gn_silu_k<<<dim3(NB * 8), blk, 0, stream>>>(f2, f1, dec_gn2_g + i * 256, dec_gn2_b + i * 256);
      conv3_k<<<dim3(NB * 32, 4), blk, 0, stream>>>(f1, wf_dec_c2 + i * 196608, dec_c2_b + i * 256, f0, f0);
    }
    conv_out_k<<<dim3(NB * 32), blk, 0, stream>>>(f0, wf_dec_out, dec_out_b, xhat + (size_t)b0 * 2048 * 36);
  }

  // ---- losses / scalars ----
  loss_k<<<dim3(256), blk, 0, stream>>>(x, xhat, mask, scal);
  finalize_k<<<dim3(1), blk, 0, stream>>>(counts, scal, (float*)d_out + 2375680);
  codesf_k<<<dim3(64), blk, 0, stream>>>(codes, (float*)d_out + 2359296);
}